// Round 4
// baseline (74.439 us; speedup 1.0000x reference)
//
#include <hip/hip_runtime.h>
#include <hip/hip_bf16.h>

// Problem constants: B=4, Q=256, K=256, H=512
#define B_ 4
#define Q_ 256
#define K_ 256
#define H_ 512
#define NEG (-1e9f)
// pre-scale folded into projections: 2*log2(e), so exp2(q'+k') = e^{2(q+k)}
#define PRESCALE 2.885390081777927f

// ---------------------------------------------------------------------------
// Kernel 1: fp32 projection GEMM, q and k rows combined.
// rows 0..1023 = query@Wq -> qp[b][q][h] (row-major)
// rows 1024..2047 = key@Wk -> kpT[b][h][k] (TRANSPOSED via LDS bounce)
// 64x64 tile, K-step 32, 512 threads, grid (32, 8).
// Fully-masked key tiles (k0 >= valid_len[b]) are skipped.
// ---------------------------------------------------------------------------
__global__ __launch_bounds__(512) void proj_kernel(
    const float* __restrict__ Xq, const float* __restrict__ Xk,
    const float* __restrict__ Wq, const float* __restrict__ Wk,
    float* __restrict__ outq, float* __restrict__ outkT,
    const int* __restrict__ vlen)
{
    const int rt   = blockIdx.x;          // 0..31
    const int z    = rt >> 4;             // 0 = q, 1 = k
    const int row0 = (rt & 15) * 64;
    if (z) {
        const int bb = row0 >> 8, k0 = row0 & 255;
        if (k0 >= vlen[bb]) return;       // masked kp cols never read downstream
    }
    const float* X = z ? Xk : Xq;
    const float* W = z ? Wk : Wq;

    __shared__ float ldsb[2 * 32 * 68];   // As[32][68] | Bs[32][68]; reused as T[64][65]
    float (*As)[68] = (float(*)[68])ldsb;
    float (*Bs)[68] = (float(*)[68])(ldsb + 32 * 68);

    const int col0 = blockIdx.y * 64;
    const int t  = threadIdx.x;
    const int tr = t >> 4;        // 0..31 -> rows 2tr, 2tr+1
    const int tc = t & 15;        // cols 4tc..4tc+3

    const int arow = t >> 3;        // 0..63
    const int akc  = (t & 7) * 4;   // k offset
    const int bk   = t >> 4;        // 0..31
    const int bc   = (t & 15) * 4;

    float acc[2][4] = {};

    for (int kk = 0; kk < H_; kk += 32) {
        const float4 av = *(const float4*)&X[(size_t)(row0 + arow) * H_ + kk + akc];
        const float4 bv = *(const float4*)&W[(size_t)(kk + bk) * H_ + col0 + bc];
        __syncthreads();                  // prev-iter LDS reads done
        As[akc + 0][arow] = av.x;
        As[akc + 1][arow] = av.y;
        As[akc + 2][arow] = av.z;
        As[akc + 3][arow] = av.w;
        *(float4*)&Bs[bk][bc] = bv;
        __syncthreads();
        #pragma unroll
        for (int k = 0; k < 32; ++k) {
            const float2 a = *(const float2*)&As[k][2 * tr];
            const float4 b = *(const float4*)&Bs[k][4 * tc];
            const float aa[2] = {a.x, a.y};
            const float bb[4] = {b.x, b.y, b.z, b.w};
            #pragma unroll
            for (int i = 0; i < 2; ++i)
                #pragma unroll
                for (int j = 0; j < 4; ++j)
                    acc[i][j] = __builtin_fmaf(aa[i], bb[j], acc[i][j]);
        }
    }

    if (!z) {
        // direct row-major write
        #pragma unroll
        for (int i = 0; i < 2; ++i) {
            float4 o = make_float4(acc[i][0] * PRESCALE, acc[i][1] * PRESCALE,
                                   acc[i][2] * PRESCALE, acc[i][3] * PRESCALE);
            *(float4*)&outq[(size_t)(row0 + 2 * tr + i) * H_ + col0 + 4 * tc] = o;
        }
    } else {
        // transpose via LDS bounce: kpT[(b*H + h)*K + k]
        __syncthreads();                  // all As/Bs reads done before reuse
        float (*T)[65] = (float(*)[65])ldsb;   // 64x65 = 16.6 KB fits in 17.4 KB
        #pragma unroll
        for (int i = 0; i < 2; ++i)
            #pragma unroll
            for (int j = 0; j < 4; ++j)
                T[2 * tr + i][4 * tc + j] = acc[i][j] * PRESCALE;
        __syncthreads();
        const int hh = t >> 3;            // 0..63 (local h)
        const int m0 = (t & 7) * 8;       // 0..56 (local k)
        float v[8];
        #pragma unroll
        for (int m = 0; m < 8; ++m) v[m] = T[m0 + m][hh];   // stride 65: conflict-free
        const int bb = row0 >> 8, k0 = row0 & 255;
        float* dst = &outkT[((size_t)bb * H_ + col0 + hh) * K_ + k0 + m0];
        ((float4*)dst)[0] = make_float4(v[0], v[1], v[2], v[3]);
        ((float4*)dst)[1] = make_float4(v[4], v[5], v[6], v[7]);
    }
}

// ---------------------------------------------------------------------------
// Kernel 2: fused scores -> masked softmax -> context.
// grid = (Q/2, B) = (128, 4), block = 256 (4 waves) -> 2 blocks/CU, b-mixed.
// Score: wave w owns k-slice [64w, 64w+64), lane = one k; within-lane h-loop
//   streams kpT[b][h][k] from global (coalesced, L2-resident); q/wm from LDS
//   as bulk float4 broadcasts. NO barriers in the loop. Wave skips entirely
//   if 64w >= valid.  score(q,k) = sum_h -2*w_h * rcp(1 + e^{2(q_h+k_h)}).
// Softmax: waves 0,1 (row = wave). Context: wave w owns its k-slice,
//   4-partial LDS tree reduce.
// ---------------------------------------------------------------------------
__global__ __launch_bounds__(256) void fused_attn(
    const float* __restrict__ qp, const float* __restrict__ kpT,
    const float* __restrict__ value, const int* __restrict__ vlen,
    const float* __restrict__ wv, float* __restrict__ out)
{
    const int qt = blockIdx.x;        // 0..127
    const int b  = blockIdx.y;        // 0..3
    const int q0 = qt * 2;
    const int t    = threadIdx.x;
    const int wave = t >> 6;          // 0..3
    const int lane = t & 63;

    __shared__ float q2[H_][2];       // 4 KB, [h][qi], pre-scaled
    __shared__ float wm[H_];          // 2 KB, -2*wv
    __shared__ float sc[2][K_];       // 2 KB
    __shared__ float ctxp[4][2][H_];  // 16 KB

    const int valid = vlen[b];

    // one-time staging
    if (t < 256) {
        const int qi = t >> 7, p4 = (t & 127) * 4;
        const float4 v = *(const float4*)&qp[((size_t)b * Q_ + q0 + qi) * H_ + p4];
        q2[p4 + 0][qi] = v.x; q2[p4 + 1][qi] = v.y;
        q2[p4 + 2][qi] = v.z; q2[p4 + 3][qi] = v.w;
        if (t < 128) {
            const float4 w = *(const float4*)&wv[t * 4];
            *(float4*)&wm[t * 4] =
                make_float4(-2.f * w.x, -2.f * w.y, -2.f * w.z, -2.f * w.w);
        }
    }
    __syncthreads();

    // ---- score phase: barrier-free, per-lane k column ----
    const int kq = wave * 64 + lane;
    if (wave * 64 < valid) {
        const float* kcol = kpT + (size_t)b * H_ * K_ + kq;
        float a0 = 0.f, a1 = 0.f;
        #pragma unroll 2
        for (int h = 0; h < H_; h += 8) {
            float qv[16], w8[8], kv[8];
            *(float4*)&qv[0]  = *(const float4*)&q2[h + 0][0];
            *(float4*)&qv[4]  = *(const float4*)&q2[h + 2][0];
            *(float4*)&qv[8]  = *(const float4*)&q2[h + 4][0];
            *(float4*)&qv[12] = *(const float4*)&q2[h + 6][0];
            *(float4*)&w8[0]  = *(const float4*)&wm[h];
            *(float4*)&w8[4]  = *(const float4*)&wm[h + 4];
            #pragma unroll
            for (int m = 0; m < 8; ++m) kv[m] = kcol[(size_t)(h + m) * K_];
            #pragma unroll
            for (int m = 0; m < 8; ++m) {
                const float e0 = __builtin_amdgcn_exp2f(qv[2 * m + 0] + kv[m]);
                a0 = __builtin_fmaf(w8[m], __builtin_amdgcn_rcpf(e0 + 1.f), a0);
                const float e1 = __builtin_amdgcn_exp2f(qv[2 * m + 1] + kv[m]);
                a1 = __builtin_fmaf(w8[m], __builtin_amdgcn_rcpf(e1 + 1.f), a1);
            }
        }
        sc[0][kq] = a0;
        sc[1][kq] = a1;
    }
    __syncthreads();

    // ---- masked softmax (waves 0,1; row = wave) ----
    if (wave < 2) {
        const int q = wave;
        if (valid == 0) {
            #pragma unroll
            for (int j = 0; j < 4; ++j) sc[q][lane + 64 * j] = 1.0f / K_;
        } else {
            float sv[4], mx = -3e38f;
            #pragma unroll
            for (int j = 0; j < 4; ++j) {
                const int kk = lane + 64 * j;
                const float s = (kk < valid) ? sc[q][kk] : NEG;
                sv[j] = s;
                mx = fmaxf(mx, s);
            }
            #pragma unroll
            for (int d = 32; d; d >>= 1) mx = fmaxf(mx, __shfl_xor(mx, d));
            float ev[4], sum = 0.f;
            #pragma unroll
            for (int j = 0; j < 4; ++j) { ev[j] = __expf(sv[j] - mx); sum += ev[j]; }
            #pragma unroll
            for (int d = 32; d; d >>= 1) sum += __shfl_xor(sum, d);
            const float inv = 1.0f / sum;
            #pragma unroll
            for (int j = 0; j < 4; ++j) sc[q][lane + 64 * j] = ev[j] * inv;
        }
    }
    __syncthreads();

    // ---- context: wave w owns k in [64w, 64w+64) ----
    const int klim = (valid == 0) ? K_ : valid;
    const int kb   = wave * 64;
    const int kend = min(64, klim - kb);
    const int h0   = lane * 8;

    float c0[8] = {}, c1[8] = {};
    for (int kc = 0; kc < kend; ++kc) {
        const int kk = kb + kc;
        const float4* vp = (const float4*)&value[((size_t)b * K_ + kk) * H_ + h0];
        const float4 v0 = vp[0], v1 = vp[1];
        const float vr[8] = {v0.x, v0.y, v0.z, v0.w, v1.x, v1.y, v1.z, v1.w};
        const float a0 = sc[0][kk], a1 = sc[1][kk];
        #pragma unroll
        for (int j = 0; j < 8; ++j) {
            c0[j] = __builtin_fmaf(a0, vr[j], c0[j]);
            c1[j] = __builtin_fmaf(a1, vr[j], c1[j]);
        }
    }
    ((float4*)&ctxp[wave][0][h0])[0] = make_float4(c0[0], c0[1], c0[2], c0[3]);
    ((float4*)&ctxp[wave][0][h0])[1] = make_float4(c0[4], c0[5], c0[6], c0[7]);
    ((float4*)&ctxp[wave][1][h0])[0] = make_float4(c1[0], c1[1], c1[2], c1[3]);
    ((float4*)&ctxp[wave][1][h0])[1] = make_float4(c1[4], c1[5], c1[6], c1[7]);
    __syncthreads();

    if (wave < 2) {
        const int q = wave;
        float o[8];
        #pragma unroll
        for (int j = 0; j < 8; ++j)
            o[j] = (ctxp[0][q][h0 + j] + ctxp[1][q][h0 + j]) +
                   (ctxp[2][q][h0 + j] + ctxp[3][q][h0 + j]);
        float4* d = (float4*)&out[((size_t)b * Q_ + q0 + q) * H_ + h0];
        d[0] = make_float4(o[0], o[1], o[2], o[3]);
        d[1] = make_float4(o[4], o[5], o[6], o[7]);
    }
}

// ---------------------------------------------------------------------------
extern "C" void kernel_launch(void* const* d_in, const int* in_sizes, int n_in,
                              void* d_out, int out_size, void* d_ws, size_t ws_size,
                              hipStream_t stream)
{
    const float* query = (const float*)d_in[0];
    const float* key   = (const float*)d_in[1];
    const float* value = (const float*)d_in[2];
    const int*   vlen  = (const int*)  d_in[3];
    const float* Wq    = (const float*)d_in[4];
    const float* Wk    = (const float*)d_in[5];
    const float* wv    = (const float*)d_in[6];
    float*       outp  = (float*)d_out;

    float* qp  = (float*)d_ws;               // [B*Q, H] = 2 MB (pre-scaled)
    float* kpT = qp + (size_t)B_ * Q_ * H_;  // [B, H, K] = 2 MB (pre-scaled, transposed)

    dim3 g1(32, 8);                          // 256 blocks, 512 threads
    proj_kernel<<<g1, 512, 0, stream>>>(query, key, Wq, Wk, qp, kpT, vlen);

    dim3 g2(Q_ / 2, B_);                     // (128, 4) -> 2 blocks/CU, b-mixed
    fused_attn<<<g2, 256, 0, stream>>>(qp, kpT, value, vlen, wv, outp);
}

// Round 5
// 64.083 us; speedup vs baseline: 1.1616x; 1.1616x over previous
//
#include <hip/hip_runtime.h>
#include <hip/hip_bf16.h>

// Problem constants: B=4, Q=256, K=256, H=512
#define B_ 4
#define Q_ 256
#define K_ 256
#define H_ 512
#define NEG (-1e9f)
// 2*log2(e): exp2(PRESCALE*x) = e^{2x}
#define PRESCALE 2.885390081777927f

// ---------------------------------------------------------------------------
// Kernel 1: fp32 projection GEMM + EXP epilogue.
// rows 0..1023:  query@Wq -> Eq[b][q][h] = exp2(PRESCALE * q')   (row-major)
// rows 1024..2047: key@Wk -> EkT[b][h][k] = exp2(PRESCALE * k')  (transposed)
// Then score e^{2(q+k)} = Eq * EkT -- exp is hoisted out of the O(BQKH) loop.
// 64x64 tile, K-step 32, 512 threads, grid (32, 8).
// Fully-masked key tiles (k0 >= valid_len[b]) are skipped.
// ---------------------------------------------------------------------------
__global__ __launch_bounds__(512) void proj_kernel(
    const float* __restrict__ Xq, const float* __restrict__ Xk,
    const float* __restrict__ Wq, const float* __restrict__ Wk,
    float* __restrict__ Eq, float* __restrict__ EkT,
    const int* __restrict__ vlen)
{
    const int rt   = blockIdx.x;          // 0..31
    const int z    = rt >> 4;             // 0 = q, 1 = k
    const int row0 = (rt & 15) * 64;
    if (z) {
        const int bb = row0 >> 8, k0 = row0 & 255;
        if (k0 >= vlen[bb]) return;       // masked kp cols never read downstream
    }
    const float* X = z ? Xk : Xq;
    const float* W = z ? Wk : Wq;

    __shared__ float ldsb[2 * 32 * 68];   // As[32][68] | Bs[32][68]; reused as T[64][65]
    float (*As)[68] = (float(*)[68])ldsb;
    float (*Bs)[68] = (float(*)[68])(ldsb + 32 * 68);

    const int col0 = blockIdx.y * 64;
    const int t  = threadIdx.x;
    const int tr = t >> 4;        // 0..31 -> rows 2tr, 2tr+1
    const int tc = t & 15;        // cols 4tc..4tc+3

    const int arow = t >> 3;        // 0..63
    const int akc  = (t & 7) * 4;   // k offset
    const int bk   = t >> 4;        // 0..31
    const int bc   = (t & 15) * 4;

    float acc[2][4] = {};

    for (int kk = 0; kk < H_; kk += 32) {
        const float4 av = *(const float4*)&X[(size_t)(row0 + arow) * H_ + kk + akc];
        const float4 bv = *(const float4*)&W[(size_t)(kk + bk) * H_ + col0 + bc];
        __syncthreads();                  // prev-iter LDS reads done
        As[akc + 0][arow] = av.x;
        As[akc + 1][arow] = av.y;
        As[akc + 2][arow] = av.z;
        As[akc + 3][arow] = av.w;
        *(float4*)&Bs[bk][bc] = bv;
        __syncthreads();
        #pragma unroll
        for (int k = 0; k < 32; ++k) {
            const float2 a = *(const float2*)&As[k][2 * tr];
            const float4 b = *(const float4*)&Bs[k][4 * tc];
            const float aa[2] = {a.x, a.y};
            const float bb[4] = {b.x, b.y, b.z, b.w};
            #pragma unroll
            for (int i = 0; i < 2; ++i)
                #pragma unroll
                for (int j = 0; j < 4; ++j)
                    acc[i][j] = __builtin_fmaf(aa[i], bb[j], acc[i][j]);
        }
    }

    if (!z) {
        #pragma unroll
        for (int i = 0; i < 2; ++i) {
            float4 o = make_float4(
                __builtin_amdgcn_exp2f(acc[i][0] * PRESCALE),
                __builtin_amdgcn_exp2f(acc[i][1] * PRESCALE),
                __builtin_amdgcn_exp2f(acc[i][2] * PRESCALE),
                __builtin_amdgcn_exp2f(acc[i][3] * PRESCALE));
            *(float4*)&Eq[(size_t)(row0 + 2 * tr + i) * H_ + col0 + 4 * tc] = o;
        }
    } else {
        // transpose via LDS bounce: EkT[(b*H + h)*K + k] = exp2(PRESCALE * acc)
        __syncthreads();                  // all As/Bs reads done before reuse
        float (*T)[65] = (float(*)[65])ldsb;
        #pragma unroll
        for (int i = 0; i < 2; ++i)
            #pragma unroll
            for (int j = 0; j < 4; ++j)
                T[2 * tr + i][4 * tc + j] =
                    __builtin_amdgcn_exp2f(acc[i][j] * PRESCALE);
        __syncthreads();
        const int hh = t >> 3;            // 0..63 (local h)
        const int m0 = (t & 7) * 8;       // 0..56 (local k)
        float v[8];
        #pragma unroll
        for (int m = 0; m < 8; ++m) v[m] = T[m0 + m][hh];
        const int bb = row0 >> 8, k0 = row0 & 255;
        float* dst = &EkT[((size_t)bb * H_ + col0 + hh) * K_ + k0 + m0];
        ((float4*)dst)[0] = make_float4(v[0], v[1], v[2], v[3]);
        ((float4*)dst)[1] = make_float4(v[4], v[5], v[6], v[7]);
    }
}

// ---------------------------------------------------------------------------
// Kernel 2: fused scores -> masked softmax -> context.
// grid = (Q/2, B) = (128, 4), block = 512 (8 waves) -> 2 blocks/CU = 4 waves/SIMD.
// Score: thread t owns (qi = t>>8, k = t&255). h in 8-chunks; Ek tile [8][256]
//   double-buffered in LDS (each wave stages one coalesced 1KB row; load issued
//   before compute, ds_write after -> HBM/L2 latency hidden).
//   arg = fma(Eq, Ek, 1); acc = fma(-2w, rcp(arg), acc)   -- 2 VALU + 1 trans.
//   Eq/wm reads are wave-uniform LDS broadcasts (qi fixed per wave).
// Softmax: waves 0,1 (row = wave). Context: wave w owns k in [32w,32w+32),
//   5-barrier tree reduce in the 16KB scratch (reused Ek buffer).
// ---------------------------------------------------------------------------
__global__ __launch_bounds__(512) void fused_attn(
    const float* __restrict__ Eq, const float* __restrict__ EkT,
    const float* __restrict__ value, const int* __restrict__ vlen,
    const float* __restrict__ wv, float* __restrict__ out)
{
    const int qt = blockIdx.x;        // 0..127
    const int b  = blockIdx.y;        // 0..3
    const int q0 = qt * 2;
    const int t    = threadIdx.x;
    const int wave = t >> 6;          // 0..7
    const int lane = t & 63;

    __shared__ float smem[4096];      // ekbuf[2][8][256] | ctxp[4][2][512] (16 KB)
    __shared__ float eq2[2][H_];      // 4 KB
    __shared__ float wm[H_];          // 2 KB
    __shared__ float sc[2][K_];       // 2 KB

    const int valid = vlen[b];

    // one-time staging: Eq rows + (-2*wv)
    if (t < 256) {
        const int qi = t >> 7, p4 = (t & 127) * 4;
        *(float4*)&eq2[qi][p4] =
            *(const float4*)&Eq[((size_t)b * Q_ + q0 + qi) * H_ + p4];
    } else if (t < 384) {
        const int i = (t - 256) * 4;
        const float4 w = *(const float4*)&wv[i];
        *(float4*)&wm[i] = make_float4(-2.f * w.x, -2.f * w.y, -2.f * w.z, -2.f * w.w);
    }

    const int k   = t & 255;
    const int qi  = t >> 8;           // 0 or 1 (wave-uniform)
    const int hr  = wave;             // staging row 0..7
    const int sk4 = lane * 4;
    const bool sact = (sk4 < valid);
    const bool cact = (k < valid);
    const float* ekb = EkT + (size_t)b * H_ * K_;

    // prologue: stage chunk 0 into buf 0
    if (sact)
        *(float4*)&smem[hr * 256 + sk4] = *(const float4*)&ekb[(size_t)hr * K_ + sk4];
    __syncthreads();   // covers eq2, wm, chunk 0

    float acc = 0.f;
    for (int c = 0; c < 64; ++c) {
        const int buf = c & 1;
        const int h0  = c * 8;
        float4 nxt;
        const bool pf = (c < 63) && sact;
        if (pf) nxt = *(const float4*)&ekb[(size_t)(h0 + 8 + hr) * K_ + sk4];
        if (cact) {
            float eqv[8], wmv[8];
            *(float4*)&eqv[0] = *(const float4*)&eq2[qi][h0];
            *(float4*)&eqv[4] = *(const float4*)&eq2[qi][h0 + 4];
            *(float4*)&wmv[0] = *(const float4*)&wm[h0];
            *(float4*)&wmv[4] = *(const float4*)&wm[h0 + 4];
            #pragma unroll
            for (int m = 0; m < 8; ++m) {
                const float ek  = smem[(buf * 8 + m) * 256 + k];
                const float arg = __builtin_fmaf(eqv[m], ek, 1.0f);
                acc = __builtin_fmaf(wmv[m], __builtin_amdgcn_rcpf(arg), acc);
            }
        }
        if (pf) *(float4*)&smem[((buf ^ 1) * 8 + hr) * 256 + sk4] = nxt;
        __syncthreads();
    }
    if (cact) sc[qi][k] = acc;
    __syncthreads();

    // ---- masked softmax (waves 0,1; row = wave) ----
    if (wave < 2) {
        const int q = wave;
        if (valid == 0) {
            #pragma unroll
            for (int j = 0; j < 4; ++j) sc[q][lane + 64 * j] = 1.0f / K_;
        } else {
            float sv[4], mx = -3e38f;
            #pragma unroll
            for (int j = 0; j < 4; ++j) {
                const int kk = lane + 64 * j;
                const float s = (kk < valid) ? sc[q][kk] : NEG;
                sv[j] = s;
                mx = fmaxf(mx, s);
            }
            #pragma unroll
            for (int d = 32; d; d >>= 1) mx = fmaxf(mx, __shfl_xor(mx, d));
            float ev[4], sum = 0.f;
            #pragma unroll
            for (int j = 0; j < 4; ++j) { ev[j] = __expf(sv[j] - mx); sum += ev[j]; }
            #pragma unroll
            for (int d = 32; d; d >>= 1) sum += __shfl_xor(sum, d);
            const float inv = 1.0f / sum;
            #pragma unroll
            for (int j = 0; j < 4; ++j) sc[q][lane + 64 * j] = ev[j] * inv;
        }
    }
    __syncthreads();

    // ---- context: wave w owns k in [32w, 32w+32) ----
    const int klim = (valid == 0) ? K_ : valid;
    const int kb   = wave * 32;
    const int kend = min(32, klim - kb);
    const int h0   = lane * 8;

    float c0[8] = {}, c1[8] = {};
    for (int kc = 0; kc < kend; ++kc) {
        const int kk = kb + kc;
        const float4* vp = (const float4*)&value[((size_t)b * K_ + kk) * H_ + h0];
        const float4 v0 = vp[0], v1 = vp[1];
        const float vr[8] = {v0.x, v0.y, v0.z, v0.w, v1.x, v1.y, v1.z, v1.w};
        const float a0 = sc[0][kk], a1 = sc[1][kk];
        #pragma unroll
        for (int j = 0; j < 8; ++j) {
            c0[j] = __builtin_fmaf(a0, vr[j], c0[j]);
            c1[j] = __builtin_fmaf(a1, vr[j], c1[j]);
        }
    }

    // tree reduce in smem scratch: slot s at smem[s*1024 + qi*512 + h]
    #define PARK(s)                                                         \
        do {                                                                \
            float* d0 = &smem[(s) * 1024 + h0];                             \
            float* d1 = &smem[(s) * 1024 + 512 + h0];                       \
            ((float4*)d0)[0] = make_float4(c0[0], c0[1], c0[2], c0[3]);     \
            ((float4*)d0)[1] = make_float4(c0[4], c0[5], c0[6], c0[7]);     \
            ((float4*)d1)[0] = make_float4(c1[0], c1[1], c1[2], c1[3]);     \
            ((float4*)d1)[1] = make_float4(c1[4], c1[5], c1[6], c1[7]);     \
        } while (0)
    #define FOLD(s)                                                         \
        do {                                                                \
            const float* d0 = &smem[(s) * 1024 + h0];                       \
            const float* d1 = &smem[(s) * 1024 + 512 + h0];                 \
            _Pragma("unroll")                                               \
            for (int j = 0; j < 8; ++j) { c0[j] += d0[j]; c1[j] += d1[j]; } \
        } while (0)

    if (wave >= 4) PARK(wave - 4);
    __syncthreads();
    if (wave < 4) FOLD(wave);
    __syncthreads();
    if (wave == 2 || wave == 3) PARK(wave - 2);
    __syncthreads();
    if (wave < 2) FOLD(wave);
    __syncthreads();
    if (wave == 1) PARK(1);
    __syncthreads();
    if (wave == 0) {
        FOLD(1);
        float* o0 = &out[((size_t)b * Q_ + q0 + 0) * H_ + h0];
        float* o1 = &out[((size_t)b * Q_ + q0 + 1) * H_ + h0];
        ((float4*)o0)[0] = make_float4(c0[0], c0[1], c0[2], c0[3]);
        ((float4*)o0)[1] = make_float4(c0[4], c0[5], c0[6], c0[7]);
        ((float4*)o1)[0] = make_float4(c1[0], c1[1], c1[2], c1[3]);
        ((float4*)o1)[1] = make_float4(c1[4], c1[5], c1[6], c1[7]);
    }
    #undef PARK
    #undef FOLD
}

// ---------------------------------------------------------------------------
extern "C" void kernel_launch(void* const* d_in, const int* in_sizes, int n_in,
                              void* d_out, int out_size, void* d_ws, size_t ws_size,
                              hipStream_t stream)
{
    const float* query = (const float*)d_in[0];
    const float* key   = (const float*)d_in[1];
    const float* value = (const float*)d_in[2];
    const int*   vlen  = (const int*)  d_in[3];
    const float* Wq    = (const float*)d_in[4];
    const float* Wk    = (const float*)d_in[5];
    const float* wv    = (const float*)d_in[6];
    float*       outp  = (float*)d_out;

    float* EqBuf  = (float*)d_ws;                 // [B*Q, H] = 2 MB (e^{2q'})
    float* EkTBuf = EqBuf + (size_t)B_ * Q_ * H_; // [B, H, K] = 2 MB (e^{2k'}, transposed)

    dim3 g1(32, 8);                               // 256 blocks, 512 threads
    proj_kernel<<<g1, 512, 0, stream>>>(query, key, Wq, Wk, EqBuf, EkTBuf, vlen);

    dim3 g2(Q_ / 2, B_);                          // (128, 4), 512 threads
    fused_attn<<<g2, 512, 0, stream>>>(EqBuf, EkTBuf, value, vlen, wv, outp);
}

// Round 6
// 49.327 us; speedup vs baseline: 1.5091x; 1.2991x over previous
//
#include <hip/hip_runtime.h>
#include <hip/hip_bf16.h>

// Problem constants: B=4, Q=256, K=256, H=512
#define B_ 4
#define Q_ 256
#define K_ 256
#define H_ 512
#define NEG (-1e9f)
// 2*log2(e): exp2(PRESCALE*x) = e^{2x}
#define PRESCALE 2.885390081777927f

// ---------------------------------------------------------------------------
// Kernel 1: fp32 projection GEMM + EXP epilogue (unchanged from r5).
// rows 0..1023:  query@Wq -> Eq[b][q][h] = exp2(PRESCALE * q')   (row-major)
// rows 1024..2047: key@Wk -> EkT[b][h][k] = exp2(PRESCALE * k')  (transposed)
// ---------------------------------------------------------------------------
__global__ __launch_bounds__(512) void proj_kernel(
    const float* __restrict__ Xq, const float* __restrict__ Xk,
    const float* __restrict__ Wq, const float* __restrict__ Wk,
    float* __restrict__ Eq, float* __restrict__ EkT,
    const int* __restrict__ vlen)
{
    const int rt   = blockIdx.x;          // 0..31
    const int z    = rt >> 4;             // 0 = q, 1 = k
    const int row0 = (rt & 15) * 64;
    if (z) {
        const int bb = row0 >> 8, k0 = row0 & 255;
        if (k0 >= vlen[bb]) return;       // masked kp cols never read downstream
    }
    const float* X = z ? Xk : Xq;
    const float* W = z ? Wk : Wq;

    __shared__ float ldsb[2 * 32 * 68];   // As[32][68] | Bs[32][68]; reused as T[64][65]
    float (*As)[68] = (float(*)[68])ldsb;
    float (*Bs)[68] = (float(*)[68])(ldsb + 32 * 68);

    const int col0 = blockIdx.y * 64;
    const int t  = threadIdx.x;
    const int tr = t >> 4;        // 0..31 -> rows 2tr, 2tr+1
    const int tc = t & 15;        // cols 4tc..4tc+3

    const int arow = t >> 3;        // 0..63
    const int akc  = (t & 7) * 4;   // k offset
    const int bk   = t >> 4;        // 0..31
    const int bc   = (t & 15) * 4;

    float acc[2][4] = {};

    for (int kk = 0; kk < H_; kk += 32) {
        const float4 av = *(const float4*)&X[(size_t)(row0 + arow) * H_ + kk + akc];
        const float4 bv = *(const float4*)&W[(size_t)(kk + bk) * H_ + col0 + bc];
        __syncthreads();                  // prev-iter LDS reads done
        As[akc + 0][arow] = av.x;
        As[akc + 1][arow] = av.y;
        As[akc + 2][arow] = av.z;
        As[akc + 3][arow] = av.w;
        *(float4*)&Bs[bk][bc] = bv;
        __syncthreads();
        #pragma unroll
        for (int k = 0; k < 32; ++k) {
            const float2 a = *(const float2*)&As[k][2 * tr];
            const float4 b = *(const float4*)&Bs[k][4 * tc];
            const float aa[2] = {a.x, a.y};
            const float bb[4] = {b.x, b.y, b.z, b.w};
            #pragma unroll
            for (int i = 0; i < 2; ++i)
                #pragma unroll
                for (int j = 0; j < 4; ++j)
                    acc[i][j] = __builtin_fmaf(aa[i], bb[j], acc[i][j]);
        }
    }

    if (!z) {
        #pragma unroll
        for (int i = 0; i < 2; ++i) {
            float4 o = make_float4(
                __builtin_amdgcn_exp2f(acc[i][0] * PRESCALE),
                __builtin_amdgcn_exp2f(acc[i][1] * PRESCALE),
                __builtin_amdgcn_exp2f(acc[i][2] * PRESCALE),
                __builtin_amdgcn_exp2f(acc[i][3] * PRESCALE));
            *(float4*)&Eq[(size_t)(row0 + 2 * tr + i) * H_ + col0 + 4 * tc] = o;
        }
    } else {
        // transpose via LDS bounce: EkT[(b*H + h)*K + k] = exp2(PRESCALE * acc)
        __syncthreads();                  // all As/Bs reads done before reuse
        float (*T)[65] = (float(*)[65])ldsb;
        #pragma unroll
        for (int i = 0; i < 2; ++i)
            #pragma unroll
            for (int j = 0; j < 4; ++j)
                T[2 * tr + i][4 * tc + j] =
                    __builtin_amdgcn_exp2f(acc[i][j] * PRESCALE);
        __syncthreads();
        const int hh = t >> 3;            // 0..63 (local h)
        const int m0 = (t & 7) * 8;       // 0..56 (local k)
        float v[8];
        #pragma unroll
        for (int m = 0; m < 8; ++m) v[m] = T[m0 + m][hh];
        const int bb = row0 >> 8, k0 = row0 & 255;
        float* dst = &EkT[((size_t)bb * H_ + col0 + hh) * K_ + k0 + m0];
        ((float4*)dst)[0] = make_float4(v[0], v[1], v[2], v[3]);
        ((float4*)dst)[1] = make_float4(v[4], v[5], v[6], v[7]);
    }
}

// ---------------------------------------------------------------------------
// Kernel 2: fused scores -> masked softmax -> context.
// grid = (Q/2, B) = (128, 4), block = 512 (8 waves) -> 2 blocks/CU, 4 waves/SIMD.
// Score phase (barrier-free, LDS-light):
//   wave w owns k-band [32w, 32w+32); whole-wave skip if band >= valid.
//   lane = (ho = lane>>3, kg = lane&7); thread owns 2 q-rows x 4 k
//   (k = band + 4*kg) and h-slice {ho, ho+8, ho+16, ...} (64 steps).
//   Per step: Ek b128 GLOBAL read (L2-resident, vector pipe), Eq b64 + wm b32
//   LDS broadcasts. acc = fma(wm, rcp(fma(eq, ek, 1)), acc) -- 2 VALU + 1 trans.
//   h-partials combined with 3 shfl_xor (ho bits 3..5); lanes ho==0 write sc.
// Softmax: waves 0,1 (row = wave). Context: wave w owns its 32-k band;
//   3-level LDS tree reduce into out.
// ---------------------------------------------------------------------------
__global__ __launch_bounds__(512) void fused_attn(
    const float* __restrict__ Eq, const float* __restrict__ EkT,
    const float* __restrict__ value, const int* __restrict__ vlen,
    const float* __restrict__ wv, float* __restrict__ out)
{
    const int qt = blockIdx.x;        // 0..127
    const int b  = blockIdx.y;        // 0..3
    const int q0 = qt * 2;
    const int t    = threadIdx.x;
    const int wave = t >> 6;          // 0..7
    const int lane = t & 63;

    __shared__ float eqh[H_][2];      // 4 KB  [h][qi]
    __shared__ float wm[H_];          // 2 KB  (-2 * wv)
    __shared__ float sc[2][K_];       // 2 KB
    __shared__ float ctxp[4][2][H_];  // 16 KB reduce scratch

    const int valid = vlen[b];

    // ---- one-time staging: eqh (transposed) + wm ----
    if (t < 256) {
        const int qi = t >> 7, p4 = (t & 127) * 4;
        const float4 v = *(const float4*)&Eq[((size_t)b * Q_ + q0 + qi) * H_ + p4];
        eqh[p4 + 0][qi] = v.x; eqh[p4 + 1][qi] = v.y;
        eqh[p4 + 2][qi] = v.z; eqh[p4 + 3][qi] = v.w;
    } else if (t < 384) {
        const int i = (t - 256) * 4;
        const float4 w = *(const float4*)&wv[i];
        *(float4*)&wm[i] = make_float4(-2.f * w.x, -2.f * w.y, -2.f * w.z, -2.f * w.w);
    }
    __syncthreads();

    // ---- score phase ----
    const int band = wave * 32;
    const int ho   = lane >> 3;       // h offset 0..7
    const int kg   = lane & 7;        // k group 0..7
    const int kq   = band + kg * 4;   // this thread's first k

    if (band < valid) {
        const float* ekp = EkT + ((size_t)b * H_ + ho) * K_ + kq;
        float a0[4] = {}, a1[4] = {};
        #pragma unroll 4
        for (int s = 0; s < 64; ++s) {
            const int h = ho + 8 * s;
            const float4 ek = *(const float4*)(ekp + (size_t)s * 8 * K_);
            const float2 eq = *(const float2*)&eqh[h][0];
            const float  w  = wm[h];
            const float ek4[4] = {ek.x, ek.y, ek.z, ek.w};
            #pragma unroll
            for (int j = 0; j < 4; ++j) {
                const float g0 = __builtin_fmaf(eq.x, ek4[j], 1.0f);
                a0[j] = __builtin_fmaf(w, __builtin_amdgcn_rcpf(g0), a0[j]);
                const float g1 = __builtin_fmaf(eq.y, ek4[j], 1.0f);
                a1[j] = __builtin_fmaf(w, __builtin_amdgcn_rcpf(g1), a1[j]);
            }
        }
        // combine h-partials across ho groups (lane bits 3..5)
        #pragma unroll
        for (int d = 8; d < 64; d <<= 1) {
            #pragma unroll
            for (int j = 0; j < 4; ++j) {
                a0[j] += __shfl_xor(a0[j], d);
                a1[j] += __shfl_xor(a1[j], d);
            }
        }
        if (ho == 0) {
            *(float4*)&sc[0][kq] = make_float4(a0[0], a0[1], a0[2], a0[3]);
            *(float4*)&sc[1][kq] = make_float4(a1[0], a1[1], a1[2], a1[3]);
        }
    }
    __syncthreads();

    // ---- masked softmax (waves 0,1; row = wave) ----
    if (wave < 2) {
        const int q = wave;
        if (valid == 0) {
            #pragma unroll
            for (int j = 0; j < 4; ++j) sc[q][lane + 64 * j] = 1.0f / K_;
        } else {
            float sv[4], mx = -3e38f;
            #pragma unroll
            for (int j = 0; j < 4; ++j) {
                const int kk = lane + 64 * j;
                const float s = (kk < valid) ? sc[q][kk] : NEG;
                sv[j] = s;
                mx = fmaxf(mx, s);
            }
            #pragma unroll
            for (int d = 32; d; d >>= 1) mx = fmaxf(mx, __shfl_xor(mx, d));
            float ev[4], sum = 0.f;
            #pragma unroll
            for (int j = 0; j < 4; ++j) { ev[j] = __expf(sv[j] - mx); sum += ev[j]; }
            #pragma unroll
            for (int d = 32; d; d >>= 1) sum += __shfl_xor(sum, d);
            const float inv = 1.0f / sum;
            #pragma unroll
            for (int j = 0; j < 4; ++j) sc[q][lane + 64 * j] = ev[j] * inv;
        }
    }
    __syncthreads();

    // ---- context: wave w owns k in [32w, 32w+32) ----
    const int klim = (valid == 0) ? K_ : valid;
    const int kb   = wave * 32;
    const int kend = min(32, klim - kb);
    const int h0   = lane * 8;

    float c0[8] = {}, c1[8] = {};
    for (int kc = 0; kc < kend; ++kc) {
        const int kk = kb + kc;
        const float4* vp = (const float4*)&value[((size_t)b * K_ + kk) * H_ + h0];
        const float4 v0 = vp[0], v1 = vp[1];
        const float vr[8] = {v0.x, v0.y, v0.z, v0.w, v1.x, v1.y, v1.z, v1.w};
        const float a0 = sc[0][kk], a1 = sc[1][kk];
        #pragma unroll
        for (int j = 0; j < 8; ++j) {
            c0[j] = __builtin_fmaf(a0, vr[j], c0[j]);
            c1[j] = __builtin_fmaf(a1, vr[j], c1[j]);
        }
    }

    // 3-level tree reduce over 8 waves
    #define PARK(s)                                                         \
        do {                                                                \
            float* d0 = &ctxp[s][0][h0];                                    \
            float* d1 = &ctxp[s][1][h0];                                    \
            ((float4*)d0)[0] = make_float4(c0[0], c0[1], c0[2], c0[3]);     \
            ((float4*)d0)[1] = make_float4(c0[4], c0[5], c0[6], c0[7]);     \
            ((float4*)d1)[0] = make_float4(c1[0], c1[1], c1[2], c1[3]);     \
            ((float4*)d1)[1] = make_float4(c1[4], c1[5], c1[6], c1[7]);     \
        } while (0)
    #define FOLD(s)                                                         \
        do {                                                                \
            const float* d0 = &ctxp[s][0][h0];                              \
            const float* d1 = &ctxp[s][1][h0];                              \
            _Pragma("unroll")                                               \
            for (int j = 0; j < 8; ++j) { c0[j] += d0[j]; c1[j] += d1[j]; } \
        } while (0)

    if (wave >= 4) PARK(wave - 4);
    __syncthreads();
    if (wave < 4) FOLD(wave);
    __syncthreads();
    if (wave == 2 || wave == 3) PARK(wave - 2);
    __syncthreads();
    if (wave < 2) FOLD(wave);
    __syncthreads();
    if (wave == 1) PARK(1);
    __syncthreads();
    if (wave == 0) {
        FOLD(1);
        float* o0 = &out[((size_t)b * Q_ + q0 + 0) * H_ + h0];
        float* o1 = &out[((size_t)b * Q_ + q0 + 1) * H_ + h0];
        ((float4*)o0)[0] = make_float4(c0[0], c0[1], c0[2], c0[3]);
        ((float4*)o0)[1] = make_float4(c0[4], c0[5], c0[6], c0[7]);
        ((float4*)o1)[0] = make_float4(c1[0], c1[1], c1[2], c1[3]);
        ((float4*)o1)[1] = make_float4(c1[4], c1[5], c1[6], c1[7]);
    }
    #undef PARK
    #undef FOLD
}

// ---------------------------------------------------------------------------
extern "C" void kernel_launch(void* const* d_in, const int* in_sizes, int n_in,
                              void* d_out, int out_size, void* d_ws, size_t ws_size,
                              hipStream_t stream)
{
    const float* query = (const float*)d_in[0];
    const float* key   = (const float*)d_in[1];
    const float* value = (const float*)d_in[2];
    const int*   vlen  = (const int*)  d_in[3];
    const float* Wq    = (const float*)d_in[4];
    const float* Wk    = (const float*)d_in[5];
    const float* wv    = (const float*)d_in[6];
    float*       outp  = (float*)d_out;

    float* EqBuf  = (float*)d_ws;                 // [B*Q, H] = 2 MB (e^{2q'})
    float* EkTBuf = EqBuf + (size_t)B_ * Q_ * H_; // [B, H, K] = 2 MB (e^{2k'}, transposed)

    dim3 g1(32, 8);                               // 256 blocks, 512 threads
    proj_kernel<<<g1, 512, 0, stream>>>(query, key, Wq, Wk, EqBuf, EkTBuf, vlen);

    dim3 g2(Q_ / 2, B_);                          // (128, 4), 512 threads
    fused_attn<<<g2, 512, 0, stream>>>(EqBuf, EkTBuf, value, vlen, wv, outp);
}